// Round 3
// baseline (95.924 us; speedup 1.0000x reference)
//
#include <hip/hip_runtime.h>
#include <stdint.h>

// Problem constants (fixed by reference)
#define N_S 256   // samples
#define K_C 64    // clusters
#define T_L 128   // seq len (contraction dim)
#define F_D 64    // features

typedef short short8 __attribute__((ext_vector_type(8)));
typedef float float4v __attribute__((ext_vector_type(4)));

// ------------------------------------------------------------------
// Kernel 1: fp32 (row,T,F) -> bf16 (F,row,T) transpose + row sum-of-squares.
// One wave per source row; lane = f. Per t-step the wave reads 64 consecutive
// floats (256B, perfectly coalesced). Each lane packs 8 consecutive-t bf16
// into one 16B store.
// ------------------------------------------------------------------
__global__ __launch_bounds__(256) void k_convert(
    const float* __restrict__ x, const float* __restrict__ c,
    uint16_t* __restrict__ xb, uint16_t* __restrict__ cb,
    float* __restrict__ x2, float* __restrict__ c2)
{
    const int tid  = threadIdx.x;
    const int lane = tid & 63;   // feature index
    const int w    = tid >> 6;   // wave in block
    const int b    = blockIdx.x;

    const float* src;
    uint16_t*    dst;
    float*       sq;
    if (b < 64) {                       // inputs: rows are samples
        const int row = b * 4 + w;      // 0..255
        src = x + (size_t)row * T_L * F_D;
        dst = xb + (size_t)lane * N_S * T_L + (size_t)row * T_L;
        sq  = x2 + row * F_D + lane;
    } else {                            // clusters: rows are clusters
        const int row = (b - 64) * 4 + w;  // 0..63
        src = c + (size_t)row * T_L * F_D;
        dst = cb + (size_t)lane * K_C * T_L + (size_t)row * T_L;
        sq  = c2 + row * F_D + lane;
    }

    float acc = 0.f;
    for (int t0 = 0; t0 < T_L; t0 += 8) {
        union { uint16_t h[8]; uint4 v; } buf;
        #pragma unroll
        for (int j = 0; j < 8; ++j) {
            float v = src[(t0 + j) * F_D + lane];
            acc = fmaf(v, v, acc);
            uint32_t u = __float_as_uint(v);
            uint32_t r = (u + 0x7FFFu + ((u >> 16) & 1u)) >> 16;  // RNE to bf16
            buf.h[j] = (uint16_t)r;
        }
        *reinterpret_cast<uint4*>(dst + t0) = buf.v;
    }
    *sq = acc;
}

// ------------------------------------------------------------------
// Kernel 2: distance (N,K) via bf16 MFMA.
// Grid: 64 blocks = 16 n-tiles x 4 k-tiles. Block: 512 threads = 8 waves,
// wave w handles f-chunk [8w, 8w+8). Each wave computes a 16x16 (n,k) tile:
// per f, 4 chained mfma_f32_16x16x32_bf16 over T=128, then epilogue
// d += sqrt(relu(x2 + c2 - 2*xc)). Cross-wave f-reduce via LDS, direct store.
// A and B fragments use the identical lane->(row, t) load pattern, so the
// result is robust to the exact intra-32 t permutation.
// ------------------------------------------------------------------
__global__ __launch_bounds__(512) void k_dist(
    const uint16_t* __restrict__ xb, const uint16_t* __restrict__ cb,
    const float* __restrict__ x2, const float* __restrict__ c2,
    float* __restrict__ dist)
{
    const int tid  = threadIdx.x;
    const int lane = tid & 63;
    const int w    = tid >> 6;          // 0..7 : f-chunk
    const int nt   = blockIdx.x >> 2;   // 0..15
    const int kt   = blockIdx.x & 3;    // 0..3
    const int n0   = nt * 16, k0 = kt * 16;
    const int row  = lane & 15;         // operand row (sample for A, cluster for B)
    const int tg   = lane >> 4;         // 0..3 : t-subgroup
    const int f0   = w * 8;

    __shared__ float red[8][16][17];

    float dsum[4] = {0.f, 0.f, 0.f, 0.f};

    const uint16_t* abase = xb + (size_t)(n0 + row) * T_L + (size_t)tg * 8;
    const uint16_t* bbase = cb + (size_t)(k0 + row) * T_L + (size_t)tg * 8;

    #pragma unroll
    for (int f = 0; f < 8; ++f) {
        const int ff = f0 + f;
        const short8* ap = reinterpret_cast<const short8*>(abase + (size_t)ff * N_S * T_L);
        const short8* bp = reinterpret_cast<const short8*>(bbase + (size_t)ff * K_C * T_L);
        float4v acc = {0.f, 0.f, 0.f, 0.f};
        #pragma unroll
        for (int ts = 0; ts < 4; ++ts) {   // t += 32 per MFMA
            short8 a = ap[ts * 4];          // short8 index: 8 elems each -> 32 t
            short8 bfr = bp[ts * 4];
            acc = __builtin_amdgcn_mfma_f32_16x16x32_bf16(a, bfr, acc, 0, 0, 0);
        }
        // Epilogue: C/D layout col = lane&15 (cluster), row m = tg*4+reg (sample)
        const float c2v = c2[(k0 + row) * F_D + ff];
        #pragma unroll
        for (int r = 0; r < 4; ++r) {
            const int m = tg * 4 + r;
            const float x2v = x2[(n0 + m) * F_D + ff];
            float d2 = fmaf(-2.0f, acc[r], x2v + c2v);
            dsum[r] += sqrtf(fmaxf(d2, 0.f));
        }
    }

    #pragma unroll
    for (int r = 0; r < 4; ++r) red[w][tg * 4 + r][row] = dsum[r];
    __syncthreads();

    if (tid < 256) {
        const int m = tid >> 4, kl = tid & 15;
        float s = 0.f;
        #pragma unroll
        for (int ww = 0; ww < 8; ++ww) s += red[ww][m][kl];
        dist[(n0 + m) * K_C + (k0 + kl)] = s;
    }
}

// ------------------------------------------------------------------
// Kernel 3: q = softmax_k( 1/(1+dist^2) )  (alpha=1 -> exponent is 1)
// One wave per sample row (lane = k). Also accumulates column sums of q
// (block pre-reduction, then one atomicAdd per column per block).
// ------------------------------------------------------------------
__global__ __launch_bounds__(256) void k_softmax(
    const float* __restrict__ dist, float* __restrict__ q,
    float* __restrict__ colsum)
{
    const int tid  = threadIdx.x;
    const int lane = tid & 63;
    const int w    = tid >> 6;
    const int n    = blockIdx.x * 4 + w;

    const float d = dist[n * K_C + lane];
    const float v = 1.0f / fmaf(d, d, 1.0f);

    float m = v;
    #pragma unroll
    for (int off = 32; off; off >>= 1) m = fmaxf(m, __shfl_xor(m, off));
    const float e = __expf(v - m);
    float s = e;
    #pragma unroll
    for (int off = 32; off; off >>= 1) s += __shfl_xor(s, off);
    const float qv = e / s;

    q[n * K_C + lane] = qv;

    __shared__ float part[4][64];
    part[w][lane] = qv;
    __syncthreads();
    if (tid < 64) {
        float t = part[0][tid] + part[1][tid] + part[2][tid] + part[3][tid];
        atomicAdd(&colsum[tid], t);
    }
}

// ------------------------------------------------------------------
// Kernel 4: p = softmax_k(q^2 / colsum);  loss = sum(q*(log q - p)) / N
// One wave per row; wave-reduce the KL term, block-reduce, one atomic.
// ------------------------------------------------------------------
__global__ __launch_bounds__(256) void k_loss(
    const float* __restrict__ q, const float* __restrict__ colsum,
    float* __restrict__ loss)
{
    const int tid  = threadIdx.x;
    const int lane = tid & 63;
    const int w    = tid >> 6;
    const int n    = blockIdx.x * 4 + w;

    const float qv = q[n * K_C + lane];
    const float s  = qv * qv / colsum[lane];

    float m = s;
    #pragma unroll
    for (int off = 32; off; off >>= 1) m = fmaxf(m, __shfl_xor(m, off));
    const float e = __expf(s - m);
    float se = e;
    #pragma unroll
    for (int off = 32; off; off >>= 1) se += __shfl_xor(se, off);
    const float p = e / se;

    float term = qv * (__logf(qv) - p);
    #pragma unroll
    for (int off = 32; off; off >>= 1) term += __shfl_xor(term, off);

    __shared__ float part[4];
    if (lane == 0) part[w] = term;
    __syncthreads();
    if (tid == 0) {
        const float t = (part[0] + part[1] + part[2] + part[3]) * (1.0f / N_S);
        atomicAdd(loss, t);
    }
}

// ------------------------------------------------------------------
// ws layout (bytes):
//   xb : bf16 (F,N,T)  = 4,194,304
//   cb : bf16 (F,K,T)  = 1,048,576   @ 4194304
//   x2 : f32  (N,F)    =    65,536   @ 5242880
//   c2 : f32  (K,F)    =    16,384   @ 5308416
//   dist: f32 (N,K)    =    65,536   @ 5324800
//   colsum: f32 (K)    =       256   @ 5390336
// total ~5.4 MB
// ------------------------------------------------------------------
extern "C" void kernel_launch(void* const* d_in, const int* in_sizes, int n_in,
                              void* d_out, int out_size, void* d_ws, size_t ws_size,
                              hipStream_t stream)
{
    const float* x = (const float*)d_in[0];
    const float* c = (const float*)d_in[1];
    float* out = (float*)d_out;

    char* ws = (char*)d_ws;
    uint16_t* xb     = (uint16_t*)(ws);
    uint16_t* cb     = (uint16_t*)(ws + 4194304);
    float*    x2     = (float*)(ws + 5242880);
    float*    c2     = (float*)(ws + 5308416);
    float*    dist   = (float*)(ws + 5324800);
    float*    colsum = (float*)(ws + 5390336);

    float* q    = out;          // (N,K) = 16384 f32
    float* loss = out + 16384;  // scalar

    hipMemsetAsync(colsum, 0, K_C * sizeof(float), stream);
    hipMemsetAsync(loss, 0, sizeof(float), stream);

    k_convert<<<80, 256, 0, stream>>>(x, c, xb, cb, x2, c2);
    k_dist   <<<64, 512, 0, stream>>>(xb, cb, x2, c2, dist);
    k_softmax<<<64, 256, 0, stream>>>(dist, q, colsum);
    k_loss   <<<64, 256, 0, stream>>>(q, colsum, loss);
}